// Round 2
// baseline (98.302 us; speedup 1.0000x reference)
//
#include <hip/hip_runtime.h>

#define BATCH  65536
#define NIN    9
#define NHID   100
#define TSTEPS 25
#define CHUNK  5
#define EPS    3e-5f

typedef float v2f __attribute__((ext_vector_type(2)));

// ROUND-18b (retry after container failure; source identical to R18).
// Register-budget fix. rocprof showed VGPR_Count=44 while live per-thread
// state (a0[25]+a1[25]+xv[9]+chain) needs >=65 VGPRs -> the allocator was
// shuffling accumulators through AGPRs/scratch (extra VALU moves on an
// issue-bound kernel). Grid is exactly 4 blocks/CU, so occupancy >4
// waves/EU is unreachable: __launch_bounds__(256,4) unlocks a 128-VGPR
// budget at zero occupancy cost. Plus: j-loop unroll 2 (two independent
// u-chains hide fmaf->cmp->cndmask latency + weight s_load latency), and
// paired margin updates fuse to v_min3_f32 (abs mods free).
// Numerics bit-identical: same fmaf sequences, same f64 arbiter patching.
__global__ __launch_bounds__(256, 4) void snn_kernel(
    const float* __restrict__ x,  const float* __restrict__ W1,
    const float* __restrict__ b1, const float* __restrict__ W2,
    const float* __restrict__ b2, float* __restrict__ out)
{
    __shared__ float sx[64 * NIN];              // 2.25 KB staged x rows
    __shared__ v2f   sacc[2][4][CHUNK][64];     // 20.5 KB double-buffered reduce

    const int tid  = threadIdx.x;
    const int lane = tid & 63;
    const int wq   = __builtin_amdgcn_readfirstlane(tid >> 6);
    const int b0   = blockIdx.x * 64;

    for (int i = tid; i < 64 * NIN; i += 256) sx[i] = x[(size_t)b0 * NIN + i];
    __syncthreads();

    // per-lane x row, f32 (exact input values)
    float xv[NIN];
#pragma unroll
    for (int i = 0; i < NIN; ++i) xv[i] = sx[lane * NIN + i];

    // per-step fc2 partial sums: SCALAR floats (no v2f, no f64)
    float a0[TSTEPS], a1[TSTEPS];
#pragma unroll
    for (int t = 0; t < TSTEPS; ++t) { a0[t] = 0.f; a1[t] = 0.f; }

    const int h0 = wq * 25;
#pragma unroll 2
    for (int j = 0; j < 25; ++j) {
        const int h = h0 + j;                  // wave-uniform -> s_load weights
        float c32 = 0.f;
#pragma unroll
        for (int i = 0; i < NIN; ++i) c32 = fmaf(W1[h * NIN + i], xv[i], c32);
        c32 += b1[h];
        const float k  = c32 - 0.05f;          // u-chain: u = m-1
        const float k1 = c32 - 1.05f;
        const float w0 = W2[h], w1 = W2[NHID + h];

        float u = -1.0f, ming = 1e30f;
        bool  s = false;                       // spike(t-1) == reset(t)
#pragma unroll
        for (int t = 0; t < TSTEPS - 1; t += 2) {
            // step t
            u = fmaf(0.95f, u, s ? k1 : k);    // leaky integrate + fused reset
            s = (u > 0.0f);                    // spike (== m > 1)
            const float au = fabsf(u);         // margin, deferred into min3
            const float d = s ? 1.f : 0.f;
            a0[t] = fmaf(d, w0, a0[t]);
            a1[t] = fmaf(d, w1, a1[t]);
            // step t+1
            u = fmaf(0.95f, u, s ? k1 : k);
            s = (u > 0.0f);
            ming = fminf(fminf(au, fabsf(u)), ming);  // -> v_min3_f32 w/ |.|
            const float d2 = s ? 1.f : 0.f;
            a0[t + 1] = fmaf(d2, w0, a0[t + 1]);
            a1[t + 1] = fmaf(d2, w1, a1[t + 1]);
        }
        {   // step 24 tail (TSTEPS odd)
            u = fmaf(0.95f, u, s ? k1 : k);
            s = (u > 0.0f);
            ming = fminf(ming, fabsf(u));
            const float d = s ? 1.f : 0.f;
            a0[TSTEPS - 1] = fmaf(d, w0, a0[TSTEPS - 1]);
            a1[TSTEPS - 1] = fmaf(d, w1, a1[TSTEPS - 1]);
        }

        // rare wave-uniform exact fallback: f32 replay (bit-identical: same
        // fmaf sequence, same inputs) vs the EXACT f64 chain of rounds 2-14;
        // patch acc where decisions differ -> spike trains track the f64
        // numpy arbiter everywhere.
        if (__any(ming < EPS)) {
            double c64 = 0.0;
#pragma unroll
            for (int i = 0; i < NIN; ++i)
                c64 += (double)W1[h * NIN + i] * (double)xv[i];
            c64 += (double)b1[h];
            const double c1 = c64 - 1.0;

            double md = 0.0;  bool sd = false;   // exact f64 chain
            float  ur = -1.0f; bool sr = false;  // f32 replay
#pragma unroll
            for (int t = 0; t < TSTEPS; ++t) {
                ur = fmaf(0.95f, ur, sr ? k1 : k);
                sr = (ur > 0.0f);
                md = 0.95 * md + (sd ? c1 : c64);
                sd = (md > 1.0);
                if (sr != sd) {                  // patch to the f64 decision
                    float sg = sd ? 1.f : -1.f;
                    a0[t] = fmaf(sg, w0, a0[t]);
                    a1[t] = fmaf(sg, w1, a1[t]);
                }
            }
        }
    }

    // chunked cross-wave reduce + mem2 (wave 0), double-buffered LDS.
    // All acc indices compile-time constants (round-9 lesson).
    double m20 = 0.0, m21 = 0.0;
    double bb0 = (double)b2[0], bb1 = (double)b2[1];

#pragma unroll
    for (int k = 0; k < TSTEPS / CHUNK; ++k) {
#pragma unroll
        for (int u = 0; u < CHUNK; ++u)
            sacc[k & 1][wq][u][lane] = (v2f){a0[k * CHUNK + u], a1[k * CHUNK + u]};
        __syncthreads();
        // wave0 reads buf[k&1] before the NEXT barrier; other waves can't
        // overwrite buf[k&1] until chunk k+2's writes, behind that barrier.
        if (wq == 0) {
#pragma unroll
            for (int u = 0; u < CHUNK; ++u) {
                const int t = k * CHUNK + u;
                v2f q0 = sacc[k & 1][0][u][lane];
                v2f q1 = sacc[k & 1][1][u][lane];
                v2f q2 = sacc[k & 1][2][u][lane];
                v2f q3 = sacc[k & 1][3][u][lane];
                v2f sum = (q0 + q1) + (q2 + q3);   // butterfly bracketing
                double r0 = (m20 > 1.0) ? 1.0 : 0.0;
                double r1 = (m21 > 1.0) ? 1.0 : 0.0;
                m20 = 0.95 * m20 + ((double)sum[0] + bb0) - r0;
                m21 = 0.95 * m21 + ((double)sum[1] + bb1) - r1;
                *(float2*)(out + ((size_t)t * BATCH + b0 + lane) * 2) =
                    make_float2((float)m20, (float)m21);
            }
        }
    }
}

extern "C" void kernel_launch(void* const* d_in, const int* in_sizes, int n_in,
                              void* d_out, int out_size, void* d_ws, size_t ws_size,
                              hipStream_t stream) {
    const float* x  = (const float*)d_in[0];
    const float* W1 = (const float*)d_in[1];
    const float* b1 = (const float*)d_in[2];
    const float* W2 = (const float*)d_in[3];
    const float* b2 = (const float*)d_in[4];
    float* out = (float*)d_out;

    dim3 grid(BATCH / 64), block(256);
    hipLaunchKernelGGL(snn_kernel, grid, block, 0, stream, x, W1, b1, W2, b2, out);
}